// Round 11
// baseline (356.618 us; speedup 1.0000x reference)
//
#include <hip/hip_runtime.h>

#define NN 100000
#define NE 1600000
#define NBUCK 782   // ceil(NN/128), bucket = node >> 7
#define PCHUNK 4096 // edges per k_pairs block -> 391 blocks
#define HISTB 256   // k_hist grid
#define NREP 8      // replicated bucket-count copies

struct alignas(8) US4 { unsigned short x, y, z, w; };

__device__ __forceinline__ float bfu(unsigned int hw) { return __uint_as_float(hw << 16); }
__device__ __forceinline__ unsigned short f2bf(float f) {
    unsigned int u = __float_as_uint(f);
    return (unsigned short)((u + 0x7fffu + ((u >> 16) & 1u)) >> 16);
}

// ---------------- build: dual bucket-ordered edge arrays ----------------

// LDS-only dual histogram (dst buckets + src buckets), replicated global merge.
__global__ __launch_bounds__(256) void k_hist(const int* __restrict__ src,
                                              const int* __restrict__ dst,
                                              int* __restrict__ bcnt8_d,
                                              int* __restrict__ bcnt8_s) {
    __shared__ int hd[NBUCK], hs[NBUCK];
    int tid = threadIdx.x;
    for (int i = tid; i < NBUCK; i += 256) { hd[i] = 0; hs[i] = 0; }
    __syncthreads();
    int* md = bcnt8_d + (size_t)(blockIdx.x & (NREP - 1)) * NBUCK;
    int* ms = bcnt8_s + (size_t)(blockIdx.x & (NREP - 1)) * NBUCK;
    int stride = gridDim.x * 256;
    for (int e = blockIdx.x * 256 + tid; e < NE; e += stride) {
        atomicAdd(&hd[dst[e] >> 7], 1);
        atomicAdd(&hs[src[e] >> 7], 1);
    }
    __syncthreads();
    for (int i = tid; i < NBUCK; i += 256) {
        if (hd[i]) atomicAdd(&md[i], hd[i]);
        if (hs[i]) atomicAdd(&ms[i], hs[i]);
    }
}

// block 0: scan dst buckets; block 1: scan src buckets
__global__ __launch_bounds__(1024) void k_bscan(const int* __restrict__ bcnt8_d,
                                                const int* __restrict__ bcnt8_s,
                                                int* __restrict__ base_d,
                                                int* __restrict__ cursor_d,
                                                int* __restrict__ base_s,
                                                int* __restrict__ cursor_s) {
    __shared__ int tmp[1024];
    int t = threadIdx.x;
    const int* bc = blockIdx.x ? bcnt8_s : bcnt8_d;
    int* base = blockIdx.x ? base_s : base_d;
    int* cur = blockIdx.x ? cursor_s : cursor_d;
    int v = 0;
    if (t < NBUCK)
#pragma unroll
        for (int c = 0; c < NREP; ++c) v += bc[c * NBUCK + t];
    tmp[t] = v;
    __syncthreads();
    for (int off = 1; off < 1024; off <<= 1) {
        int u = (t >= off) ? tmp[t - off] : 0;
        __syncthreads();
        tmp[t] += u;
        __syncthreads();
    }
    int excl = tmp[t] - v;
    if (t < NBUCK) {
        base[t] = excl;
        cur[t] = excl;
    }
    if (t == 0) base[NBUCK] = NE;
}

// dual LDS-binned scatter: bulk reservation per (block,bucket), packed words
// into per-block contiguous runs.  E2d = (src<<7)|(dst&127); E2s = src&127 (byte).
__global__ __launch_bounds__(256) void k_pairs(const int* __restrict__ src,
                                               const int* __restrict__ dst,
                                               int* __restrict__ cursor_d,
                                               int* __restrict__ cursor_s,
                                               int* __restrict__ E2d,
                                               unsigned char* __restrict__ E2s) {
    __shared__ int hist_d[NBUCK], gbase_d[NBUCK], hist_s[NBUCK], gbase_s[NBUCK];
    int tid = threadIdx.x;
    for (int i = tid; i < NBUCK; i += 256) { hist_d[i] = 0; hist_s[i] = 0; }
    __syncthreads();
    int base = blockIdx.x * PCHUNK;
#pragma unroll
    for (int i = 0; i < PCHUNK / 256; ++i) {
        int e = base + i * 256 + tid;
        if (e < NE) {
            atomicAdd(&hist_d[dst[e] >> 7], 1);
            atomicAdd(&hist_s[src[e] >> 7], 1);
        }
    }
    __syncthreads();
    // rotate reservation start per block to decorrelate cursor-line contention
    int rot = (int)((blockIdx.x * 191u) % NBUCK);
    for (int ii = tid; ii < NBUCK; ii += 256) {
        int i = ii + rot;
        if (i >= NBUCK) i -= NBUCK;
        int h = hist_d[i];
        if (h) gbase_d[i] = atomicAdd(&cursor_d[i], h);
        hist_d[i] = 0;
        h = hist_s[i];
        if (h) gbase_s[i] = atomicAdd(&cursor_s[i], h);
        hist_s[i] = 0;
    }
    __syncthreads();
#pragma unroll
    for (int i = 0; i < PCHUNK / 256; ++i) {
        int e = base + i * 256 + tid;
        if (e < NE) {
            int s = src[e], d = dst[e];
            int bd = d >> 7;
            int pd = atomicAdd(&hist_d[bd], 1);
            E2d[gbase_d[bd] + pd] = (s << 7) | (d & 127);
            int bs = s >> 7;
            int ps = atomicAdd(&hist_s[bs], 1);
            E2s[gbase_s[bs] + ps] = (unsigned char)(s & 127);
        }
    }
}

// merged per-bucket node pass.  b < NBUCK: dst bucket -> row_start, r_in, csr.
// b >= NBUCK: src bucket -> r_out (out-degree rsqrt).
__global__ __launch_bounds__(256) void k_nodes(const int* __restrict__ E2d,
                                               const int* __restrict__ base_d,
                                               const unsigned char* __restrict__ E2s,
                                               const int* __restrict__ base_s,
                                               int* __restrict__ row_start,
                                               float* __restrict__ r_in,
                                               float* __restrict__ r_out,
                                               int* __restrict__ csr) {
    __shared__ int cnt[128], cur[128];
    int tid = threadIdx.x;
    int b = blockIdx.x;
    if (b >= NBUCK) {  // ---- out-degree count ----
        b -= NBUCK;
        int base = base_s[b], end = base_s[b + 1];
        if (tid < 128) cnt[tid] = 0;
        __syncthreads();
        for (int i = base + tid; i < end; i += 256) atomicAdd(&cnt[E2s[i]], 1);
        __syncthreads();
        if (tid < 128) {
            int node = b * 128 + tid;
            if (node < NN) r_out[node] = rsqrtf((float)max(cnt[tid], 1));
        }
        return;
    }
    // ---- per-node CSR within dst bucket ----
    int base = base_d[b], end = base_d[b + 1];
    if (tid < 128) cnt[tid] = 0;
    __syncthreads();
    for (int i = base + tid; i < end; i += 256) atomicAdd(&cnt[E2d[i] & 127], 1);
    __syncthreads();
    int v = (tid < 128) ? cnt[tid] : 0;
    for (int off = 1; off < 128; off <<= 1) {
        int u = (tid >= off && tid < 128) ? cnt[tid - off] : 0;
        __syncthreads();
        if (tid < 128) cnt[tid] += u;
        __syncthreads();
    }
    if (tid < 128) {
        int excl = cnt[tid] - v;  // exclusive scan within bucket
        cur[tid] = excl;
        int node = b * 128 + tid;
        if (node <= NN) row_start[node] = base + excl;
        if (node < NN) r_in[node] = rsqrtf((float)max(v, 1));
    }
    __syncthreads();
    for (int i = base + tid; i < end; i += 256) {
        int e = E2d[i];
        int pos = atomicAdd(&cur[e & 127], 1);
        csr[base + pos] = e >> 7;
    }
}

// ---------------- dense GEMMs ----------------

// A(bf16) = (x @ W0) * r_out.  64 nodes/block, thread = 4m x 4n, K=128 in two halves.
__global__ __launch_bounds__(256) void k_gemm0(const float* __restrict__ x,
                                               const float* __restrict__ W0,
                                               const float* __restrict__ r_out,
                                               unsigned short* __restrict__ A) {
    __shared__ float xl[64 * 129];
    __shared__ float wl[64 * 64];
    int tid = threadIdx.x;
    int m0 = blockIdx.x * 64;
#pragma unroll
    for (int i = 0; i < 8; ++i) {
        int idx = i * 256 + tid;
        int m = idx >> 5, kc = idx & 31;
        int gm = min(m0 + m, NN - 1);
        float4 v = *(const float4*)&x[(size_t)gm * 128 + kc * 4];
        float* p = &xl[m * 129 + kc * 4];
        p[0] = v.x; p[1] = v.y; p[2] = v.z; p[3] = v.w;
    }
    int tn = tid & 15, tm = tid >> 4;
    float acc[4][4] = {};
    const float4* W4 = (const float4*)W0;
    float4* wl4 = (float4*)wl;
    for (int h = 0; h < 2; ++h) {
        __syncthreads();
#pragma unroll
        for (int i = 0; i < 4; ++i) wl4[i * 256 + tid] = W4[h * 1024 + i * 256 + tid];
        __syncthreads();
#pragma unroll 4
        for (int k = 0; k < 64; ++k) {
            int kk = h * 64 + k;
            float4 wv = *(const float4*)&wl[k * 64 + tn * 4];
            float xv[4];
#pragma unroll
            for (int i = 0; i < 4; ++i) xv[i] = xl[(tm * 4 + i) * 129 + kk];
#pragma unroll
            for (int i = 0; i < 4; ++i) {
                acc[i][0] = fmaf(xv[i], wv.x, acc[i][0]);
                acc[i][1] = fmaf(xv[i], wv.y, acc[i][1]);
                acc[i][2] = fmaf(xv[i], wv.z, acc[i][2]);
                acc[i][3] = fmaf(xv[i], wv.w, acc[i][3]);
            }
        }
    }
#pragma unroll
    for (int i = 0; i < 4; ++i) {
        int m = m0 + tm * 4 + i;
        if (m < NN) {
            float ro = r_out[m];
            US4 o = {f2bf(acc[i][0] * ro), f2bf(acc[i][1] * ro),
                     f2bf(acc[i][2] * ro), f2bf(acc[i][3] * ro)};
            *(US4*)&A[(size_t)m * 64 + tn * 4] = o;
        }
    }
}

// C = (relu(G @ W1 + b1) @ W2) * r_out.  G is bf16.  64 nodes/block.
__global__ __launch_bounds__(256) void k_mlp(const unsigned short* __restrict__ G,
                                             const float* __restrict__ W1,
                                             const float* __restrict__ b1,
                                             const float* __restrict__ W2,
                                             const float* __restrict__ r_out,
                                             float* __restrict__ C) {
    __shared__ float gl[64 * 65];
    __shared__ float w1l[64 * 64];
    __shared__ float w2l[64 * 16];
    int tid = threadIdx.x;
    int m0 = blockIdx.x * 64;
#pragma unroll
    for (int i = 0; i < 2; ++i) {
        int idx = i * 256 + tid;  // 512 chunks of 8 bf16
        int m = idx >> 3, c8 = idx & 7;
        int gm = min(m0 + m, NN - 1);
        uint4 u = *(const uint4*)&G[(size_t)gm * 64 + c8 * 8];
        float* p = &gl[m * 65 + c8 * 8];
        p[0] = bfu(u.x & 0xffffu); p[1] = bfu(u.x >> 16);
        p[2] = bfu(u.y & 0xffffu); p[3] = bfu(u.y >> 16);
        p[4] = bfu(u.z & 0xffffu); p[5] = bfu(u.z >> 16);
        p[6] = bfu(u.w & 0xffffu); p[7] = bfu(u.w >> 16);
    }
    float4* w1l4 = (float4*)w1l;
    const float4* W1_4 = (const float4*)W1;
#pragma unroll
    for (int i = 0; i < 4; ++i) w1l4[i * 256 + tid] = W1_4[i * 256 + tid];
    ((float4*)w2l)[tid] = ((const float4*)W2)[tid];
    __syncthreads();
    int tn = tid & 15, tm = tid >> 4;
    float acc[4][4] = {};
#pragma unroll 4
    for (int k = 0; k < 64; ++k) {
        float4 wv = *(const float4*)&w1l[k * 64 + tn * 4];
        float xv[4];
#pragma unroll
        for (int i = 0; i < 4; ++i) xv[i] = gl[(tm * 4 + i) * 65 + k];
#pragma unroll
        for (int i = 0; i < 4; ++i) {
            acc[i][0] = fmaf(xv[i], wv.x, acc[i][0]);
            acc[i][1] = fmaf(xv[i], wv.y, acc[i][1]);
            acc[i][2] = fmaf(xv[i], wv.z, acc[i][2]);
            acc[i][3] = fmaf(xv[i], wv.w, acc[i][3]);
        }
    }
    float4 bb = *(const float4*)&b1[tn * 4];
    __syncthreads();
#pragma unroll
    for (int i = 0; i < 4; ++i) {
        gl[(tm * 4 + i) * 65 + tn * 4 + 0] = fmaxf(acc[i][0] + bb.x, 0.f);
        gl[(tm * 4 + i) * 65 + tn * 4 + 1] = fmaxf(acc[i][1] + bb.y, 0.f);
        gl[(tm * 4 + i) * 65 + tn * 4 + 2] = fmaxf(acc[i][2] + bb.z, 0.f);
        gl[(tm * 4 + i) * 65 + tn * 4 + 3] = fmaxf(acc[i][3] + bb.w, 0.f);
    }
    __syncthreads();
    int m = tid >> 2, n0 = (tid & 3) * 4;
    float a2[4] = {};
#pragma unroll 8
    for (int k = 0; k < 64; ++k) {
        float zv = gl[m * 65 + k];
        float4 wv = *(const float4*)&w2l[k * 16 + n0];
        a2[0] = fmaf(zv, wv.x, a2[0]);
        a2[1] = fmaf(zv, wv.y, a2[1]);
        a2[2] = fmaf(zv, wv.z, a2[2]);
        a2[3] = fmaf(zv, wv.w, a2[3]);
    }
    int node = m0 + m;
    if (node < NN) {
        float ro = r_out[node];
        float4 o = {a2[0] * ro, a2[1] * ro, a2[2] * ro, a2[3] * ro};
        *(float4*)&C[(size_t)node * 16 + n0] = o;
    }
}

// ---------------- gathers (register-accumulate, per-node wave) ----------------

// d=64 bf16 gather, 1 node/wave. 8 lanes/edge x uint4 (16B): 8 edge-groups x
// 2-deep ILP = 16-edge step, half the vmem instrs of the uint2 version.
// MODE 0: o16 = bf16(relu(agg*r_in + bias)*r_out)   (layer0 -> B)
// MODE 1: o16 = bf16(agg*r_in)                      (layer1 -> G, feeds k_mlp)
template <int MODE>
__global__ __launch_bounds__(256) void k_gather64(const int* __restrict__ row_start,
                                                  const int* __restrict__ csr,
                                                  const unsigned short* __restrict__ h,
                                                  const float* __restrict__ r_in,
                                                  const float* __restrict__ r_out,
                                                  const float* __restrict__ bias,
                                                  unsigned short* __restrict__ o16) {
    int tid = threadIdx.x;
    int wave = tid >> 6, lane = tid & 63;
    int n = blockIdx.x * 4 + wave;
    int jb = row_start[n], je = row_start[n + 1];
    int g = lane >> 3, f8 = lane & 7;  // g: edge group [0,8), f8: feature octet [0,8)
    float a0[8] = {}, a1[8] = {};
    for (int j = jb; j < je; j += 16) {
        int i0 = j + g, i1 = i0 + 8;
        int s0 = csr[min(i0, je - 1)];
        int s1 = csr[min(i1, je - 1)];
        uint4 u0 = *(const uint4*)(h + (size_t)s0 * 64 + f8 * 8);
        uint4 u1 = *(const uint4*)(h + (size_t)s1 * 64 + f8 * 8);
        float w0 = (i0 < je) ? 1.f : 0.f;
        float w1 = (i1 < je) ? 1.f : 0.f;
        a0[0] = fmaf(w0, bfu(u0.x & 0xffffu), a0[0]);
        a0[1] = fmaf(w0, bfu(u0.x >> 16), a0[1]);
        a0[2] = fmaf(w0, bfu(u0.y & 0xffffu), a0[2]);
        a0[3] = fmaf(w0, bfu(u0.y >> 16), a0[3]);
        a0[4] = fmaf(w0, bfu(u0.z & 0xffffu), a0[4]);
        a0[5] = fmaf(w0, bfu(u0.z >> 16), a0[5]);
        a0[6] = fmaf(w0, bfu(u0.w & 0xffffu), a0[6]);
        a0[7] = fmaf(w0, bfu(u0.w >> 16), a0[7]);
        a1[0] = fmaf(w1, bfu(u1.x & 0xffffu), a1[0]);
        a1[1] = fmaf(w1, bfu(u1.x >> 16), a1[1]);
        a1[2] = fmaf(w1, bfu(u1.y & 0xffffu), a1[2]);
        a1[3] = fmaf(w1, bfu(u1.y >> 16), a1[3]);
        a1[4] = fmaf(w1, bfu(u1.z & 0xffffu), a1[4]);
        a1[5] = fmaf(w1, bfu(u1.z >> 16), a1[5]);
        a1[6] = fmaf(w1, bfu(u1.w & 0xffffu), a1[6]);
        a1[7] = fmaf(w1, bfu(u1.w >> 16), a1[7]);
    }
#pragma unroll
    for (int k = 0; k < 8; ++k) a0[k] += a1[k];
#pragma unroll
    for (int m = 8; m <= 32; m <<= 1) {
#pragma unroll
        for (int k = 0; k < 8; ++k) a0[k] += __shfl_xor(a0[k], m);
    }
    if (g == 0) {
        float ri = r_in[n];
        unsigned short ov[8];
        if (MODE == 0) {
            float ro = r_out[n];
            float4 bA = *(const float4*)&bias[f8 * 8];
            float4 bB = *(const float4*)&bias[f8 * 8 + 4];
            float bb[8] = {bA.x, bA.y, bA.z, bA.w, bB.x, bB.y, bB.z, bB.w};
#pragma unroll
            for (int k = 0; k < 8; ++k)
                ov[k] = f2bf(fmaxf(fmaf(a0[k], ri, bb[k]), 0.f) * ro);
        } else {
#pragma unroll
            for (int k = 0; k < 8; ++k) ov[k] = f2bf(a0[k] * ri);
        }
        uint4 o;
        o.x = (unsigned)ov[0] | ((unsigned)ov[1] << 16);
        o.y = (unsigned)ov[2] | ((unsigned)ov[3] << 16);
        o.z = (unsigned)ov[4] | ((unsigned)ov[5] << 16);
        o.w = (unsigned)ov[6] | ((unsigned)ov[7] << 16);
        *(uint4*)&o16[(size_t)n * 64 + f8 * 8] = o;
    }
}

// d=16 fp32 gather: out = agg*r_in + b2
__global__ __launch_bounds__(256) void k_gather16(const int* __restrict__ row_start,
                                                  const int* __restrict__ csr,
                                                  const float* __restrict__ C,
                                                  const float* __restrict__ r_in,
                                                  const float* __restrict__ b2,
                                                  float* __restrict__ out) {
    int tid = threadIdx.x;
    int wave = tid >> 6, lane = tid & 63;
    int n = blockIdx.x * 4 + wave;
    int jb = row_start[n], je = row_start[n + 1];
    int g = lane >> 2, f = lane & 3;
    float4 acc = {0, 0, 0, 0};
    for (int j = jb; j < je; j += 16) {
        int i0 = j + g;
        int s = csr[min(i0, je - 1)];
        float4 v = *(const float4*)&C[(size_t)s * 16 + f * 4];
        float w = (i0 < je) ? 1.f : 0.f;
        acc.x = fmaf(w, v.x, acc.x); acc.y = fmaf(w, v.y, acc.y);
        acc.z = fmaf(w, v.z, acc.z); acc.w = fmaf(w, v.w, acc.w);
    }
#pragma unroll
    for (int m = 4; m <= 32; m <<= 1) {
        acc.x += __shfl_xor(acc.x, m); acc.y += __shfl_xor(acc.y, m);
        acc.z += __shfl_xor(acc.z, m); acc.w += __shfl_xor(acc.w, m);
    }
    if (g == 0) {
        float ri = r_in[n];
        float4 bb = *(const float4*)&b2[f * 4];
        float4 o;
        o.x = fmaf(acc.x, ri, bb.x); o.y = fmaf(acc.y, ri, bb.y);
        o.z = fmaf(acc.z, ri, bb.z); o.w = fmaf(acc.w, ri, bb.w);
        *(float4*)&out[(size_t)n * 16 + f * 4] = o;
    }
}

extern "C" void kernel_launch(void* const* d_in, const int* in_sizes, int n_in,
                              void* d_out, int out_size, void* d_ws, size_t ws_size,
                              hipStream_t stream) {
    const float* feats = (const float*)d_in[0];
    const int* src = (const int*)d_in[1];
    const int* dst = (const int*)d_in[2];
    const float* W0 = (const float*)d_in[3];
    const float* b0 = (const float*)d_in[4];
    const float* W1 = (const float*)d_in[5];
    const float* b1 = (const float*)d_in[6];
    const float* W2 = (const float*)d_in[7];
    const float* b2 = (const float*)d_in[8];
    float* out = (float*)d_out;

    // ws (4B units):
    //   r_out[NN] | r_in[NN] | row_start[NN+16] | csr[NE] | E2s[NE bytes = NE/4] |
    //   R1[32NN] (E2d[NE] then A[bf16] then G[bf16]) | R2[32NN] (B bf16) |
    //   C[16NN] | base_d[NBUCK+1] cursor_d[NBUCK] base_s[NBUCK+1] cursor_s[NBUCK]
    //   bcnt8_d[8*NBUCK] bcnt8_s[8*NBUCK]
    float* ws = (float*)d_ws;
    float* r_out = ws;
    float* r_in = ws + NN;
    int* row_start = (int*)(ws + 2 * NN);
    int* csr = (int*)(ws + 3 * NN + 16);
    unsigned char* E2s = (unsigned char*)(ws + 3 * NN + 16 + NE);
    float* R1 = ws + 3 * NN + 16 + NE + NE / 4;
    float* R2 = R1 + (size_t)32 * NN;
    float* C = R2 + (size_t)32 * NN;
    int* base_d = (int*)(C + (size_t)16 * NN);  // NBUCK+1
    int* cursor_d = base_d + NBUCK + 1;
    int* base_s = cursor_d + NBUCK;             // NBUCK+1
    int* cursor_s = base_s + NBUCK + 1;
    int* bcnt8_d = cursor_s + NBUCK;            // 8*NBUCK
    int* bcnt8_s = bcnt8_d + NREP * NBUCK;      // 8*NBUCK

    int* E2d = (int*)R1;
    unsigned short* A = (unsigned short*)R1;  // after k_nodes (E2d dead)
    unsigned short* G = A;                    // after gather<0> (A dead)
    unsigned short* B = (unsigned short*)R2;

    // build (no per-node scatter atomics anywhere)
    hipMemsetAsync(bcnt8_d, 0, 2 * NREP * NBUCK * sizeof(int), stream);
    k_hist<<<HISTB, 256, 0, stream>>>(src, dst, bcnt8_d, bcnt8_s);
    k_bscan<<<2, 1024, 0, stream>>>(bcnt8_d, bcnt8_s, base_d, cursor_d, base_s, cursor_s);
    k_pairs<<<(NE + PCHUNK - 1) / PCHUNK, 256, 0, stream>>>(src, dst, cursor_d, cursor_s,
                                                            E2d, E2s);
    k_nodes<<<2 * NBUCK, 256, 0, stream>>>(E2d, base_d, E2s, base_s,
                                           row_start, r_in, r_out, csr);

    // layer 0
    k_gemm0<<<(NN + 63) / 64, 256, 0, stream>>>(feats, W0, r_out, A);
    k_gather64<0><<<NN / 4, 256, 0, stream>>>(row_start, csr, A, r_in, r_out, b0, B);

    // layer 1 (+ layer2 pre-GEMM)
    k_gather64<1><<<NN / 4, 256, 0, stream>>>(row_start, csr, B, r_in, r_out, b0, G);
    k_mlp<<<(NN + 63) / 64, 256, 0, stream>>>(G, W1, b1, W2, r_out, C);

    // layer 2
    k_gather16<<<NN / 4, 256, 0, stream>>>(row_start, csr, C, r_in, b2, out);
}

// Round 12
// 352.044 us; speedup vs baseline: 1.0130x; 1.0130x over previous
//
#include <hip/hip_runtime.h>

#define NN 100000
#define NE 1600000
#define NBUCK 782   // ceil(NN/128), bucket = node >> 7
#define PCHUNK 4096 // edges per k_pairs block -> 391 blocks
#define HISTB 256   // k_hist grid
#define NREP 8      // replicated bucket-count copies
#define STAGE_CAP 6144  // k_nodes LDS staging capacity (avg bucket 2046, >40 sigma)

struct alignas(8) US4 { unsigned short x, y, z, w; };

__device__ __forceinline__ float bfu(unsigned int hw) { return __uint_as_float(hw << 16); }
__device__ __forceinline__ unsigned short f2bf(float f) {
    unsigned int u = __float_as_uint(f);
    return (unsigned short)((u + 0x7fffu + ((u >> 16) & 1u)) >> 16);
}

// ---------------- build: dual bucket-ordered edge arrays ----------------

// LDS-only dual histogram (dst buckets + src buckets), replicated global merge.
__global__ __launch_bounds__(256) void k_hist(const int* __restrict__ src,
                                              const int* __restrict__ dst,
                                              int* __restrict__ bcnt8_d,
                                              int* __restrict__ bcnt8_s) {
    __shared__ int hd[NBUCK], hs[NBUCK];
    int tid = threadIdx.x;
    for (int i = tid; i < NBUCK; i += 256) { hd[i] = 0; hs[i] = 0; }
    __syncthreads();
    int* md = bcnt8_d + (size_t)(blockIdx.x & (NREP - 1)) * NBUCK;
    int* ms = bcnt8_s + (size_t)(blockIdx.x & (NREP - 1)) * NBUCK;
    int stride = gridDim.x * 256;
    for (int e = blockIdx.x * 256 + tid; e < NE; e += stride) {
        atomicAdd(&hd[dst[e] >> 7], 1);
        atomicAdd(&hs[src[e] >> 7], 1);
    }
    __syncthreads();
    for (int i = tid; i < NBUCK; i += 256) {
        if (hd[i]) atomicAdd(&md[i], hd[i]);
        if (hs[i]) atomicAdd(&ms[i], hs[i]);
    }
}

// block 0: scan dst buckets; block 1: scan src buckets
__global__ __launch_bounds__(1024) void k_bscan(const int* __restrict__ bcnt8_d,
                                                const int* __restrict__ bcnt8_s,
                                                int* __restrict__ base_d,
                                                int* __restrict__ cursor_d,
                                                int* __restrict__ base_s,
                                                int* __restrict__ cursor_s) {
    __shared__ int tmp[1024];
    int t = threadIdx.x;
    const int* bc = blockIdx.x ? bcnt8_s : bcnt8_d;
    int* base = blockIdx.x ? base_s : base_d;
    int* cur = blockIdx.x ? cursor_s : cursor_d;
    int v = 0;
    if (t < NBUCK)
#pragma unroll
        for (int c = 0; c < NREP; ++c) v += bc[c * NBUCK + t];
    tmp[t] = v;
    __syncthreads();
    for (int off = 1; off < 1024; off <<= 1) {
        int u = (t >= off) ? tmp[t - off] : 0;
        __syncthreads();
        tmp[t] += u;
        __syncthreads();
    }
    int excl = tmp[t] - v;
    if (t < NBUCK) {
        base[t] = excl;
        cur[t] = excl;
    }
    if (t == 0) base[NBUCK] = NE;
}

// dual LDS-binned scatter: bulk reservation per (block,bucket), packed words
// into per-block contiguous runs.  E2d = (src<<7)|(dst&127); E2s = src&127 (byte).
__global__ __launch_bounds__(256) void k_pairs(const int* __restrict__ src,
                                               const int* __restrict__ dst,
                                               int* __restrict__ cursor_d,
                                               int* __restrict__ cursor_s,
                                               int* __restrict__ E2d,
                                               unsigned char* __restrict__ E2s) {
    __shared__ int hist_d[NBUCK], gbase_d[NBUCK], hist_s[NBUCK], gbase_s[NBUCK];
    int tid = threadIdx.x;
    for (int i = tid; i < NBUCK; i += 256) { hist_d[i] = 0; hist_s[i] = 0; }
    __syncthreads();
    int base = blockIdx.x * PCHUNK;
#pragma unroll
    for (int i = 0; i < PCHUNK / 256; ++i) {
        int e = base + i * 256 + tid;
        if (e < NE) {
            atomicAdd(&hist_d[dst[e] >> 7], 1);
            atomicAdd(&hist_s[src[e] >> 7], 1);
        }
    }
    __syncthreads();
    // rotate reservation start per block to decorrelate cursor-line contention
    int rot = (int)((blockIdx.x * 191u) % NBUCK);
    for (int ii = tid; ii < NBUCK; ii += 256) {
        int i = ii + rot;
        if (i >= NBUCK) i -= NBUCK;
        int h = hist_d[i];
        if (h) gbase_d[i] = atomicAdd(&cursor_d[i], h);
        hist_d[i] = 0;
        h = hist_s[i];
        if (h) gbase_s[i] = atomicAdd(&cursor_s[i], h);
        hist_s[i] = 0;
    }
    __syncthreads();
#pragma unroll
    for (int i = 0; i < PCHUNK / 256; ++i) {
        int e = base + i * 256 + tid;
        if (e < NE) {
            int s = src[e], d = dst[e];
            int bd = d >> 7;
            int pd = atomicAdd(&hist_d[bd], 1);
            E2d[gbase_d[bd] + pd] = (s << 7) | (d & 127);
            int bs = s >> 7;
            int ps = atomicAdd(&hist_s[bs], 1);
            E2s[gbase_s[bs] + ps] = (unsigned char)(s & 127);
        }
    }
}

// merged per-bucket node pass.  b < NBUCK: dst bucket -> row_start, r_in, csr
// (E2d staged in LDS: one global read instead of two).
// b >= NBUCK: src bucket -> r_out (out-degree rsqrt).
__global__ __launch_bounds__(256) void k_nodes(const int* __restrict__ E2d,
                                               const int* __restrict__ base_d,
                                               const unsigned char* __restrict__ E2s,
                                               const int* __restrict__ base_s,
                                               int* __restrict__ row_start,
                                               float* __restrict__ r_in,
                                               float* __restrict__ r_out,
                                               int* __restrict__ csr) {
    __shared__ int cnt[128], cur[128];
    __shared__ int stage[STAGE_CAP];  // 24 KB
    int tid = threadIdx.x;
    int b = blockIdx.x;
    if (b >= NBUCK) {  // ---- out-degree count ----
        b -= NBUCK;
        int base = base_s[b], end = base_s[b + 1];
        if (tid < 128) cnt[tid] = 0;
        __syncthreads();
        for (int i = base + tid; i < end; i += 256) atomicAdd(&cnt[E2s[i]], 1);
        __syncthreads();
        if (tid < 128) {
            int node = b * 128 + tid;
            if (node < NN) r_out[node] = rsqrtf((float)max(cnt[tid], 1));
        }
        return;
    }
    // ---- per-node CSR within dst bucket ----
    int base = base_d[b], end = base_d[b + 1];
    int m = end - base;
    bool fit = (m <= STAGE_CAP);
    if (tid < 128) cnt[tid] = 0;
    __syncthreads();
    if (fit) {
        for (int i = tid; i < m; i += 256) {
            int e = E2d[base + i];
            stage[i] = e;
            atomicAdd(&cnt[e & 127], 1);
        }
    } else {
        for (int i = base + tid; i < end; i += 256) atomicAdd(&cnt[E2d[i] & 127], 1);
    }
    __syncthreads();
    int v = (tid < 128) ? cnt[tid] : 0;
    for (int off = 1; off < 128; off <<= 1) {
        int u = (tid >= off && tid < 128) ? cnt[tid - off] : 0;
        __syncthreads();
        if (tid < 128) cnt[tid] += u;
        __syncthreads();
    }
    if (tid < 128) {
        int excl = cnt[tid] - v;  // exclusive scan within bucket
        cur[tid] = excl;
        int node = b * 128 + tid;
        if (node <= NN) row_start[node] = base + excl;
        if (node < NN) r_in[node] = rsqrtf((float)max(v, 1));
    }
    __syncthreads();
    if (fit) {
        for (int i = tid; i < m; i += 256) {
            int e = stage[i];
            int pos = atomicAdd(&cur[e & 127], 1);
            csr[base + pos] = e >> 7;
        }
    } else {
        for (int i = base + tid; i < end; i += 256) {
            int e = E2d[i];
            int pos = atomicAdd(&cur[e & 127], 1);
            csr[base + pos] = e >> 7;
        }
    }
}

// ---------------- dense GEMMs ----------------

// A(bf16) = (x @ W0) * r_out.  64 nodes/block, thread = 4m x 4n, K=128 in two halves.
__global__ __launch_bounds__(256) void k_gemm0(const float* __restrict__ x,
                                               const float* __restrict__ W0,
                                               const float* __restrict__ r_out,
                                               unsigned short* __restrict__ A) {
    __shared__ float xl[64 * 129];
    __shared__ float wl[64 * 64];
    int tid = threadIdx.x;
    int m0 = blockIdx.x * 64;
#pragma unroll
    for (int i = 0; i < 8; ++i) {
        int idx = i * 256 + tid;
        int m = idx >> 5, kc = idx & 31;
        int gm = min(m0 + m, NN - 1);
        float4 v = *(const float4*)&x[(size_t)gm * 128 + kc * 4];
        float* p = &xl[m * 129 + kc * 4];
        p[0] = v.x; p[1] = v.y; p[2] = v.z; p[3] = v.w;
    }
    int tn = tid & 15, tm = tid >> 4;
    float acc[4][4] = {};
    const float4* W4 = (const float4*)W0;
    float4* wl4 = (float4*)wl;
    for (int h = 0; h < 2; ++h) {
        __syncthreads();
#pragma unroll
        for (int i = 0; i < 4; ++i) wl4[i * 256 + tid] = W4[h * 1024 + i * 256 + tid];
        __syncthreads();
#pragma unroll 4
        for (int k = 0; k < 64; ++k) {
            int kk = h * 64 + k;
            float4 wv = *(const float4*)&wl[k * 64 + tn * 4];
            float xv[4];
#pragma unroll
            for (int i = 0; i < 4; ++i) xv[i] = xl[(tm * 4 + i) * 129 + kk];
#pragma unroll
            for (int i = 0; i < 4; ++i) {
                acc[i][0] = fmaf(xv[i], wv.x, acc[i][0]);
                acc[i][1] = fmaf(xv[i], wv.y, acc[i][1]);
                acc[i][2] = fmaf(xv[i], wv.z, acc[i][2]);
                acc[i][3] = fmaf(xv[i], wv.w, acc[i][3]);
            }
        }
    }
#pragma unroll
    for (int i = 0; i < 4; ++i) {
        int m = m0 + tm * 4 + i;
        if (m < NN) {
            float ro = r_out[m];
            US4 o = {f2bf(acc[i][0] * ro), f2bf(acc[i][1] * ro),
                     f2bf(acc[i][2] * ro), f2bf(acc[i][3] * ro)};
            *(US4*)&A[(size_t)m * 64 + tn * 4] = o;
        }
    }
}

// C16(bf16) = ((relu(G @ W1 + b1) @ W2) * r_out).  G is bf16.  64 nodes/block.
__global__ __launch_bounds__(256) void k_mlp(const unsigned short* __restrict__ G,
                                             const float* __restrict__ W1,
                                             const float* __restrict__ b1,
                                             const float* __restrict__ W2,
                                             const float* __restrict__ r_out,
                                             unsigned short* __restrict__ C16) {
    __shared__ float gl[64 * 65];
    __shared__ float w1l[64 * 64];
    __shared__ float w2l[64 * 16];
    int tid = threadIdx.x;
    int m0 = blockIdx.x * 64;
#pragma unroll
    for (int i = 0; i < 2; ++i) {
        int idx = i * 256 + tid;  // 512 chunks of 8 bf16
        int m = idx >> 3, c8 = idx & 7;
        int gm = min(m0 + m, NN - 1);
        uint4 u = *(const uint4*)&G[(size_t)gm * 64 + c8 * 8];
        float* p = &gl[m * 65 + c8 * 8];
        p[0] = bfu(u.x & 0xffffu); p[1] = bfu(u.x >> 16);
        p[2] = bfu(u.y & 0xffffu); p[3] = bfu(u.y >> 16);
        p[4] = bfu(u.z & 0xffffu); p[5] = bfu(u.z >> 16);
        p[6] = bfu(u.w & 0xffffu); p[7] = bfu(u.w >> 16);
    }
    float4* w1l4 = (float4*)w1l;
    const float4* W1_4 = (const float4*)W1;
#pragma unroll
    for (int i = 0; i < 4; ++i) w1l4[i * 256 + tid] = W1_4[i * 256 + tid];
    ((float4*)w2l)[tid] = ((const float4*)W2)[tid];
    __syncthreads();
    int tn = tid & 15, tm = tid >> 4;
    float acc[4][4] = {};
#pragma unroll 4
    for (int k = 0; k < 64; ++k) {
        float4 wv = *(const float4*)&w1l[k * 64 + tn * 4];
        float xv[4];
#pragma unroll
        for (int i = 0; i < 4; ++i) xv[i] = gl[(tm * 4 + i) * 65 + k];
#pragma unroll
        for (int i = 0; i < 4; ++i) {
            acc[i][0] = fmaf(xv[i], wv.x, acc[i][0]);
            acc[i][1] = fmaf(xv[i], wv.y, acc[i][1]);
            acc[i][2] = fmaf(xv[i], wv.z, acc[i][2]);
            acc[i][3] = fmaf(xv[i], wv.w, acc[i][3]);
        }
    }
    float4 bb = *(const float4*)&b1[tn * 4];
    __syncthreads();
#pragma unroll
    for (int i = 0; i < 4; ++i) {
        gl[(tm * 4 + i) * 65 + tn * 4 + 0] = fmaxf(acc[i][0] + bb.x, 0.f);
        gl[(tm * 4 + i) * 65 + tn * 4 + 1] = fmaxf(acc[i][1] + bb.y, 0.f);
        gl[(tm * 4 + i) * 65 + tn * 4 + 2] = fmaxf(acc[i][2] + bb.z, 0.f);
        gl[(tm * 4 + i) * 65 + tn * 4 + 3] = fmaxf(acc[i][3] + bb.w, 0.f);
    }
    __syncthreads();
    int m = tid >> 2, n0 = (tid & 3) * 4;
    float a2[4] = {};
#pragma unroll 8
    for (int k = 0; k < 64; ++k) {
        float zv = gl[m * 65 + k];
        float4 wv = *(const float4*)&w2l[k * 16 + n0];
        a2[0] = fmaf(zv, wv.x, a2[0]);
        a2[1] = fmaf(zv, wv.y, a2[1]);
        a2[2] = fmaf(zv, wv.z, a2[2]);
        a2[3] = fmaf(zv, wv.w, a2[3]);
    }
    int node = m0 + m;
    if (node < NN) {
        float ro = r_out[node];
        US4 o = {f2bf(a2[0] * ro), f2bf(a2[1] * ro), f2bf(a2[2] * ro), f2bf(a2[3] * ro)};
        *(US4*)&C16[(size_t)node * 16 + n0] = o;
    }
}

// ---------------- gathers (register-accumulate, per-node wave) ----------------

// d=64 bf16 gather, 1 node/wave. 8 lanes/edge x uint4 (16B): 8 edge-groups x
// 2-deep ILP = 16-edge step.
// MODE 0: o16 = bf16(relu(agg*r_in + bias)*r_out)   (layer0 -> B)
// MODE 1: o16 = bf16(agg*r_in)                      (layer1 -> G, feeds k_mlp)
template <int MODE>
__global__ __launch_bounds__(256) void k_gather64(const int* __restrict__ row_start,
                                                  const int* __restrict__ csr,
                                                  const unsigned short* __restrict__ h,
                                                  const float* __restrict__ r_in,
                                                  const float* __restrict__ r_out,
                                                  const float* __restrict__ bias,
                                                  unsigned short* __restrict__ o16) {
    int tid = threadIdx.x;
    int wave = tid >> 6, lane = tid & 63;
    int n = blockIdx.x * 4 + wave;
    int jb = row_start[n], je = row_start[n + 1];
    int g = lane >> 3, f8 = lane & 7;  // g: edge group [0,8), f8: feature octet [0,8)
    float a0[8] = {}, a1[8] = {};
    for (int j = jb; j < je; j += 16) {
        int i0 = j + g, i1 = i0 + 8;
        int s0 = csr[min(i0, je - 1)];
        int s1 = csr[min(i1, je - 1)];
        uint4 u0 = *(const uint4*)(h + (size_t)s0 * 64 + f8 * 8);
        uint4 u1 = *(const uint4*)(h + (size_t)s1 * 64 + f8 * 8);
        float w0 = (i0 < je) ? 1.f : 0.f;
        float w1 = (i1 < je) ? 1.f : 0.f;
        a0[0] = fmaf(w0, bfu(u0.x & 0xffffu), a0[0]);
        a0[1] = fmaf(w0, bfu(u0.x >> 16), a0[1]);
        a0[2] = fmaf(w0, bfu(u0.y & 0xffffu), a0[2]);
        a0[3] = fmaf(w0, bfu(u0.y >> 16), a0[3]);
        a0[4] = fmaf(w0, bfu(u0.z & 0xffffu), a0[4]);
        a0[5] = fmaf(w0, bfu(u0.z >> 16), a0[5]);
        a0[6] = fmaf(w0, bfu(u0.w & 0xffffu), a0[6]);
        a0[7] = fmaf(w0, bfu(u0.w >> 16), a0[7]);
        a1[0] = fmaf(w1, bfu(u1.x & 0xffffu), a1[0]);
        a1[1] = fmaf(w1, bfu(u1.x >> 16), a1[1]);
        a1[2] = fmaf(w1, bfu(u1.y & 0xffffu), a1[2]);
        a1[3] = fmaf(w1, bfu(u1.y >> 16), a1[3]);
        a1[4] = fmaf(w1, bfu(u1.z & 0xffffu), a1[4]);
        a1[5] = fmaf(w1, bfu(u1.z >> 16), a1[5]);
        a1[6] = fmaf(w1, bfu(u1.w & 0xffffu), a1[6]);
        a1[7] = fmaf(w1, bfu(u1.w >> 16), a1[7]);
    }
#pragma unroll
    for (int k = 0; k < 8; ++k) a0[k] += a1[k];
#pragma unroll
    for (int m = 8; m <= 32; m <<= 1) {
#pragma unroll
        for (int k = 0; k < 8; ++k) a0[k] += __shfl_xor(a0[k], m);
    }
    if (g == 0) {
        float ri = r_in[n];
        unsigned short ov[8];
        if (MODE == 0) {
            float ro = r_out[n];
            float4 bA = *(const float4*)&bias[f8 * 8];
            float4 bB = *(const float4*)&bias[f8 * 8 + 4];
            float bb[8] = {bA.x, bA.y, bA.z, bA.w, bB.x, bB.y, bB.z, bB.w};
#pragma unroll
            for (int k = 0; k < 8; ++k)
                ov[k] = f2bf(fmaxf(fmaf(a0[k], ri, bb[k]), 0.f) * ro);
        } else {
#pragma unroll
            for (int k = 0; k < 8; ++k) ov[k] = f2bf(a0[k] * ri);
        }
        uint4 o;
        o.x = (unsigned)ov[0] | ((unsigned)ov[1] << 16);
        o.y = (unsigned)ov[2] | ((unsigned)ov[3] << 16);
        o.z = (unsigned)ov[4] | ((unsigned)ov[5] << 16);
        o.w = (unsigned)ov[6] | ((unsigned)ov[7] << 16);
        *(uint4*)&o16[(size_t)n * 64 + f8 * 8] = o;
    }
}

// d=16 bf16 gather: out = agg*r_in + b2 (fp32 output to d_out)
__global__ __launch_bounds__(256) void k_gather16(const int* __restrict__ row_start,
                                                  const int* __restrict__ csr,
                                                  const unsigned short* __restrict__ C16,
                                                  const float* __restrict__ r_in,
                                                  const float* __restrict__ b2,
                                                  float* __restrict__ out) {
    int tid = threadIdx.x;
    int wave = tid >> 6, lane = tid & 63;
    int n = blockIdx.x * 4 + wave;
    int jb = row_start[n], je = row_start[n + 1];
    int g = lane >> 2, f = lane & 3;  // 16 groups x 4 lanes x 8B (4 bf16)
    float a[4] = {};
    for (int j = jb; j < je; j += 16) {
        int i0 = j + g;
        int s = csr[min(i0, je - 1)];
        uint2 u = *(const uint2*)(C16 + (size_t)s * 16 + f * 4);
        float w = (i0 < je) ? 1.f : 0.f;
        a[0] = fmaf(w, bfu(u.x & 0xffffu), a[0]);
        a[1] = fmaf(w, bfu(u.x >> 16), a[1]);
        a[2] = fmaf(w, bfu(u.y & 0xffffu), a[2]);
        a[3] = fmaf(w, bfu(u.y >> 16), a[3]);
    }
#pragma unroll
    for (int m = 4; m <= 32; m <<= 1) {
#pragma unroll
        for (int k = 0; k < 4; ++k) a[k] += __shfl_xor(a[k], m);
    }
    if (g == 0) {
        float ri = r_in[n];
        float4 bb = *(const float4*)&b2[f * 4];
        float4 o;
        o.x = fmaf(a[0], ri, bb.x); o.y = fmaf(a[1], ri, bb.y);
        o.z = fmaf(a[2], ri, bb.z); o.w = fmaf(a[3], ri, bb.w);
        *(float4*)&out[(size_t)n * 16 + f * 4] = o;
    }
}

extern "C" void kernel_launch(void* const* d_in, const int* in_sizes, int n_in,
                              void* d_out, int out_size, void* d_ws, size_t ws_size,
                              hipStream_t stream) {
    const float* feats = (const float*)d_in[0];
    const int* src = (const int*)d_in[1];
    const int* dst = (const int*)d_in[2];
    const float* W0 = (const float*)d_in[3];
    const float* b0 = (const float*)d_in[4];
    const float* W1 = (const float*)d_in[5];
    const float* b1 = (const float*)d_in[6];
    const float* W2 = (const float*)d_in[7];
    const float* b2 = (const float*)d_in[8];
    float* out = (float*)d_out;

    // ws (4B units):
    //   r_out[NN] | r_in[NN] | row_start[NN+16] | csr[NE] | E2s[NE bytes = NE/4] |
    //   R1[32NN] (E2d[NE] then A[bf16] then G[bf16]) | R2[32NN] (B bf16) |
    //   C16[4NN] (bf16 16/row) | base_d[NBUCK+1] cursor_d[NBUCK] base_s[NBUCK+1]
    //   cursor_s[NBUCK] | bcnt8_d[8*NBUCK] bcnt8_s[8*NBUCK]
    float* ws = (float*)d_ws;
    float* r_out = ws;
    float* r_in = ws + NN;
    int* row_start = (int*)(ws + 2 * NN);
    int* csr = (int*)(ws + 3 * NN + 16);
    unsigned char* E2s = (unsigned char*)(ws + 3 * NN + 16 + NE);
    float* R1 = ws + 3 * NN + 16 + NE + NE / 4;
    float* R2 = R1 + (size_t)32 * NN;
    float* Creg = R2 + (size_t)32 * NN;
    int* base_d = (int*)(Creg + (size_t)16 * NN);  // NBUCK+1 (C16 uses only 4NN of 16NN)
    int* cursor_d = base_d + NBUCK + 1;
    int* base_s = cursor_d + NBUCK;             // NBUCK+1
    int* cursor_s = base_s + NBUCK + 1;
    int* bcnt8_d = cursor_s + NBUCK;            // 8*NBUCK
    int* bcnt8_s = bcnt8_d + NREP * NBUCK;      // 8*NBUCK

    int* E2d = (int*)R1;
    unsigned short* A = (unsigned short*)R1;  // after k_nodes (E2d dead)
    unsigned short* G = A;                    // after gather<0> (A dead)
    unsigned short* B = (unsigned short*)R2;
    unsigned short* C16 = (unsigned short*)Creg;

    // build (no per-node scatter atomics anywhere)
    hipMemsetAsync(bcnt8_d, 0, 2 * NREP * NBUCK * sizeof(int), stream);
    k_hist<<<HISTB, 256, 0, stream>>>(src, dst, bcnt8_d, bcnt8_s);
    k_bscan<<<2, 1024, 0, stream>>>(bcnt8_d, bcnt8_s, base_d, cursor_d, base_s, cursor_s);
    k_pairs<<<(NE + PCHUNK - 1) / PCHUNK, 256, 0, stream>>>(src, dst, cursor_d, cursor_s,
                                                            E2d, E2s);
    k_nodes<<<2 * NBUCK, 256, 0, stream>>>(E2d, base_d, E2s, base_s,
                                           row_start, r_in, r_out, csr);

    // layer 0
    k_gemm0<<<(NN + 63) / 64, 256, 0, stream>>>(feats, W0, r_out, A);
    k_gather64<0><<<NN / 4, 256, 0, stream>>>(row_start, csr, A, r_in, r_out, b0, B);

    // layer 1 (+ layer2 pre-GEMM)
    k_gather64<1><<<NN / 4, 256, 0, stream>>>(row_start, csr, B, r_in, r_out, b0, G);
    k_mlp<<<(NN + 63) / 64, 256, 0, stream>>>(G, W1, b1, W2, r_out, C16);

    // layer 2
    k_gather16<<<NN / 4, 256, 0, stream>>>(row_start, csr, C16, r_in, b2, out);
}